// Round 2
// baseline (20542.249 us; speedup 1.0000x reference)
//
#include <hip/hip_runtime.h>
#include <hip/hip_bf16.h>

// LSTM recurrence: T=512, B=64, D=H=1024, gates 4H=4096.
// R2 structure:
//   1) cast_transpose Wi,Wh -> bf16 [4096][1024] (B^T layout)
//   2) chunked: xcast (x->bf16) + xgemm (xg = x@Wi, 128x128 MFMA tiles,
//      global_load_lds w16, seg-major conflict-free LDS)
//   3) persistent lstm kernel: 256 blocks, Wh slice (16 cols) resident in LDS,
//      c in registers, h double-buffered in ws, custom device-scope grid
//      barrier per step. Normal launch; residency guaranteed by capacity
//      (37KB LDS, low VGPR => >=2 blocks/CU capacity >= 512 > 256 blocks).

#define T_STEPS 512
#define BATCH   64
#define DIM     1024
#define NG      4096
#define NBLK    256

typedef __attribute__((ext_vector_type(8))) short frag8;   // 8 x bf16
typedef __attribute__((ext_vector_type(4))) float f32x4;

__device__ __forceinline__ short f2bf(float f) {
    union { float f; unsigned u; } v; v.f = f;
    unsigned r = v.u + 0x7fffu + ((v.u >> 16) & 1u);   // RNE
    return (short)(r >> 16);
}
__device__ __forceinline__ float sigm(float x) { return 1.0f / (1.0f + __expf(-x)); }
__device__ __forceinline__ float tanh_fast(float x) { return 1.0f - 2.0f / (__expf(2.0f * x) + 1.0f); }

// ---------------- prep kernels ----------------

// W: [DIM][NG] f32 row-major -> WT: [NG][DIM] bf16 row-major
__global__ __launch_bounds__(256)
void cast_transpose(const float* __restrict__ W, short* __restrict__ WT) {
    __shared__ float tile[32][33];
    int k0 = blockIdx.x * 32;
    int n0 = blockIdx.y * 32;
    int tx = threadIdx.x & 31, ty = threadIdx.x >> 5;
    #pragma unroll
    for (int i = 0; i < 32; i += 8)
        tile[ty + i][tx] = W[(size_t)(k0 + ty + i) * NG + n0 + tx];
    __syncthreads();
    #pragma unroll
    for (int i = 0; i < 32; i += 8)
        WT[(size_t)(n0 + ty + i) * DIM + k0 + tx] = f2bf(tile[tx][ty + i]);
}

__global__ __launch_bounds__(256)
void init_state(const float* __restrict__ c0, const float* __restrict__ h0,
                float* __restrict__ c, short* __restrict__ hbuf,
                unsigned* __restrict__ bar) {
    int i = blockIdx.x * 256 + threadIdx.x;
    c[i] = c0[i];
    hbuf[i] = f2bf(h0[i]);
    if (i < 8) bar[i] = 0u;
}

// f32 -> bf16, 8 elements per thread
__global__ __launch_bounds__(256)
void xcast(const float* __restrict__ x, short* __restrict__ xb, int n8) {
    int i = blockIdx.x * 256 + threadIdx.x;
    if (i >= n8) return;
    const float4* p = (const float4*)(x + (size_t)i * 8);
    float4 a = p[0], b = p[1];
    frag8 v;
    v[0] = f2bf(a.x); v[1] = f2bf(a.y); v[2] = f2bf(a.z); v[3] = f2bf(a.w);
    v[4] = f2bf(b.x); v[5] = f2bf(b.y); v[6] = f2bf(b.z); v[7] = f2bf(b.w);
    *(frag8*)(xb + (size_t)i * 8) = v;
}

// ---------------- xg GEMM: C[M][4096] = A[M][1024] * B^T, B = WiT [4096][1024]
// 128x128 tile, BK=32, 4 waves, each wave 2 m-subtiles x 8 n-subtiles.
// LDS seg-major layout: tile[seg(4)][row(128)][8 bf16] -> frag reads 2-way (free).
__global__ __launch_bounds__(256)
void xgemm(const short* __restrict__ A, const short* __restrict__ B,
           float* __restrict__ C) {
    __shared__ short As[4096];   // 8 KB
    __shared__ short Bs[4096];   // 8 KB
    const int tid = threadIdx.x;
    const int w = tid >> 6, l = tid & 63, m = l & 15, q = l >> 4;
    const size_t abase = (size_t)blockIdx.x * 128 * DIM;
    const size_t bbase = (size_t)blockIdx.y * 128 * DIM;

    f32x4 acc[2][8];
    #pragma unroll
    for (int i = 0; i < 2; ++i)
        #pragma unroll
        for (int j = 0; j < 8; ++j) acc[i][j] = (f32x4){0.f, 0.f, 0.f, 0.f};

    for (int kc = 0; kc < 32; ++kc) {
        #pragma unroll
        for (int c2 = 0; c2 < 2; ++c2) {
            int t2 = c2 * 256 + tid;
            int seg = t2 >> 7, row = t2 & 127;
            const short* ga = A + abase + (size_t)row * DIM + kc * 32 + seg * 8;
            const short* gb = B + bbase + (size_t)row * DIM + kc * 32 + seg * 8;
            __builtin_amdgcn_global_load_lds(
                (const __attribute__((address_space(1))) void*)ga,
                (__attribute__((address_space(3))) void*)(As + t2 * 8), 16, 0, 0);
            __builtin_amdgcn_global_load_lds(
                (const __attribute__((address_space(1))) void*)gb,
                (__attribute__((address_space(3))) void*)(Bs + t2 * 8), 16, 0, 0);
        }
        __syncthreads();
        frag8 a0 = *(const frag8*)(As + (q * 128 + w * 32 + m) * 8);
        frag8 a1 = *(const frag8*)(As + (q * 128 + w * 32 + 16 + m) * 8);
        #pragma unroll
        for (int nt = 0; nt < 8; ++nt) {
            frag8 bf = *(const frag8*)(Bs + (q * 128 + nt * 16 + m) * 8);
            acc[0][nt] = __builtin_amdgcn_mfma_f32_16x16x32_bf16(a0, bf, acc[0][nt], 0, 0, 0);
            acc[1][nt] = __builtin_amdgcn_mfma_f32_16x16x32_bf16(a1, bf, acc[1][nt], 0, 0, 0);
        }
        __syncthreads();
    }
    #pragma unroll
    for (int mt = 0; mt < 2; ++mt)
        #pragma unroll
        for (int nt = 0; nt < 8; ++nt)
            #pragma unroll
            for (int r = 0; r < 4; ++r) {
                int row = blockIdx.x * 128 + w * 32 + mt * 16 + q * 4 + r;
                int col = blockIdx.y * 128 + nt * 16 + m;
                C[(size_t)row * NG + col] = acc[mt][nt][r];
            }
}

// ---------------- custom grid barrier ----------------
__device__ __forceinline__ void grid_barrier(unsigned* cnt, unsigned* gen) {
    __syncthreads();
    if (threadIdx.x == 0) {
        __threadfence();   // release: publish this block's h writes
        unsigned g = __hip_atomic_load(gen, __ATOMIC_RELAXED, __HIP_MEMORY_SCOPE_AGENT);
        unsigned a = __hip_atomic_fetch_add(cnt, 1u, __ATOMIC_ACQ_REL, __HIP_MEMORY_SCOPE_AGENT);
        if (a == NBLK - 1) {
            __hip_atomic_store(cnt, 0u, __ATOMIC_RELAXED, __HIP_MEMORY_SCOPE_AGENT);
            __hip_atomic_fetch_add(gen, 1u, __ATOMIC_RELEASE, __HIP_MEMORY_SCOPE_AGENT);
        } else {
            while (__hip_atomic_load(gen, __ATOMIC_RELAXED, __HIP_MEMORY_SCOPE_AGENT) == g)
                __builtin_amdgcn_s_sleep(2);
        }
        __threadfence();   // acquire: invalidate stale lines before next step's reads
    }
    __syncthreads();
}

// ---------------- persistent recurrence ----------------
// Block k owns j0=4k: cols {g*1024 + j0 + dj} for g,dj in [0,4). Wh slice in LDS
// (frag layout [kc 32][lane 64][8]), c in registers (1/thread), h dbuf global.
__global__ __launch_bounds__(256)
void lstm_persist(const float* __restrict__ xg,     // [CT][64][4096]
                  const short* __restrict__ WhT,    // [4096][1024] bf16
                  const float* __restrict__ bias,
                  float* __restrict__ cstate,       // [64][1024] f32
                  short* __restrict__ hb0, short* __restrict__ hb1,
                  float* __restrict__ y,            // out + t0*B*H
                  unsigned* __restrict__ bar,
                  int t0, int CT) {
    __shared__ short whs[2048 * 8];   // 32 KB
    __shared__ float gsm[64][17];     // 4.25 KB
    const int tid = threadIdx.x;
    const int w = tid >> 6, l = tid & 63, m = l & 15, q4 = l >> 4;
    const int j0 = blockIdx.x * 4;

    // stage Wh slice into frag-layout LDS
    for (int idx = tid; idx < 2048; idx += 256) {
        int kcc = idx >> 6, ll = idx & 63, cc = ll & 15, qq = ll >> 4;
        int gcol = (cc >> 2) * DIM + j0 + (cc & 3);
        *(frag8*)(whs + idx * 8) =
            *(const frag8*)(WhT + (size_t)gcol * DIM + kcc * 32 + qq * 8);
    }
    const int eb = tid >> 2, ej = tid & 3;   // elementwise: batch, dj
    float creg = cstate[eb * DIM + j0 + ej];
    const float bv0 = bias[0 * DIM + j0 + ej];
    const float bv1 = bias[1 * DIM + j0 + ej];
    const float bv2 = bias[2 * DIM + j0 + ej];
    const float bv3 = bias[3 * DIM + j0 + ej];
    __syncthreads();

    for (int t = 0; t < CT; ++t) {
        const int tg = t0 + t;
        const short* hsrc = (tg & 1) ? hb1 : hb0;
        short*       hdst = (tg & 1) ? hb0 : hb1;

        // prefetch xg for elementwise phase (independent of MFMA chain)
        const float* xr = xg + ((size_t)t * BATCH + eb) * NG + j0 + ej;
        const float xv0 = xr[0], xv1 = xr[DIM], xv2 = xr[2 * DIM], xv3 = xr[3 * DIM];

        const short* hrow = hsrc + (size_t)(w * 16 + m) * DIM;
        f32x4 acc0 = {0.f, 0.f, 0.f, 0.f}, acc1 = {0.f, 0.f, 0.f, 0.f};
        #pragma unroll 8
        for (int kc = 0; kc < 32; kc += 2) {
            frag8 a0 = *(const frag8*)(hrow + kc * 32 + q4 * 8);
            frag8 b0 = *(const frag8*)(whs + (kc * 64 + l) * 8);
            acc0 = __builtin_amdgcn_mfma_f32_16x16x32_bf16(a0, b0, acc0, 0, 0, 0);
            frag8 a1 = *(const frag8*)(hrow + (kc + 1) * 32 + q4 * 8);
            frag8 b1 = *(const frag8*)(whs + ((kc + 1) * 64 + l) * 8);
            acc1 = __builtin_amdgcn_mfma_f32_16x16x32_bf16(a1, b1, acc1, 0, 0, 0);
        }
        f32x4 acc = acc0 + acc1;
        #pragma unroll
        for (int r = 0; r < 4; ++r)
            gsm[w * 16 + q4 * 4 + r][m] = acc[r];
        __syncthreads();

        const float gi = sigm(gsm[eb][ej]          + xv0 + bv0);
        const float gf = sigm(gsm[eb][4 + ej]      + xv1 + bv1);
        const float gg = tanh_fast(gsm[eb][8 + ej] + xv2 + bv2);
        const float go = sigm(gsm[eb][12 + ej]     + xv3 + bv3);
        creg = gf * creg + gi * gg;
        const float hn = go * tanh_fast(creg);
        y[((size_t)t * BATCH + eb) * DIM + j0 + ej] = hn;
        hdst[eb * DIM + j0 + ej] = f2bf(hn);

        if (t != CT - 1) grid_barrier(bar, bar + 1);
    }
    cstate[eb * DIM + j0 + ej] = creg;
}

// ---------------- host ----------------
extern "C" void kernel_launch(void* const* d_in, const int* in_sizes, int n_in,
                              void* d_out, int out_size, void* d_ws, size_t ws_size,
                              hipStream_t stream) {
    const float* x  = (const float*)d_in[0];
    const float* c0 = (const float*)d_in[1];
    const float* h0 = (const float*)d_in[2];
    const float* Wi = (const float*)d_in[3];
    const float* Wh = (const float*)d_in[4];
    const float* b  = (const float*)d_in[5];
    float* out = (float*)d_out;

    char* ws = (char*)d_ws;
    short* WiT   = (short*)(ws);                       // 8 MB
    short* WhT   = (short*)(ws + 8388608);             // 8 MB
    float* c     = (float*)(ws + 16777216);            // 256 KB
    short* hb0   = (short*)(ws + 17039360);            // 128 KB
    short* hb1   = (short*)(ws + 17170432);            // 128 KB
    unsigned* bar = (unsigned*)(ws + 17301504);        // 256 B
    const size_t fixed = 17301760;

    // pick largest chunk CT fitting ws: xbf (CT*128KB) + xg (CT*1MB)
    int CT = 2;
    const int cands[8] = {512, 256, 128, 64, 32, 16, 8, 4};
    for (int i = 0; i < 8; ++i) {
        if (fixed + (size_t)cands[i] * 1179648 <= ws_size) { CT = cands[i]; break; }
    }
    short* xbf = (short*)(ws + fixed);
    float* xg  = (float*)(ws + fixed + (size_t)CT * 131072);

    cast_transpose<<<dim3(DIM / 32, NG / 32), 256, 0, stream>>>(Wi, WiT);
    cast_transpose<<<dim3(DIM / 32, NG / 32), 256, 0, stream>>>(Wh, WhT);
    init_state<<<dim3(BATCH * DIM / 256), 256, 0, stream>>>(c0, h0, c, hb0, bar);

    const int nchunks = T_STEPS / CT;
    for (int ch = 0; ch < nchunks; ++ch) {
        const size_t xoff = (size_t)ch * CT * BATCH * DIM;
        const int n8 = CT * BATCH * DIM / 8;
        xcast<<<dim3((n8 + 255) / 256), 256, 0, stream>>>(x + xoff, xbf, n8);
        xgemm<<<dim3(CT * 64 / 128, NG / 128), 256, 0, stream>>>(xbf, WiT, xg);
        lstm_persist<<<dim3(NBLK), 256, 0, stream>>>(
            xg, WhT, b, c, hb0, hb1, out + xoff, bar, ch * CT, CT);
    }
}

// Round 3
// 4277.622 us; speedup vs baseline: 4.8023x; 4.8023x over previous
//
#include <hip/hip_runtime.h>
#include <hip/hip_bf16.h>

// LSTM recurrence: T=512, B=64, D=H=1024, gates 4H=4096.
// R3: persistent recurrence with FENCE-FREE grid barrier.
//   - h exchange: per-step fresh ring slot; writers use sc0sc1 write-through
//     (atomic relaxed, agent scope) + s_waitcnt vmcnt(0); readers use regular
//     cached loads (fresh addresses => no stale L2 lines; IF is coherence pt).
//   - barrier: per-block padded flag (relaxed store) + flag-array poll by
//     wave0. No __threadfence (which emits buffer_wbl2/buffer_inv = the R2
//     disaster: 38us/step of L2 flush), no contended fetch_add.
//   - xg precomputed TRANSPOSED [4096][M] so per-step gate reads coalesce.
//   - 512 thr/block: 8 waves = 4 batch-tiles x 2 K-halves (partial sums
//     reduced through LDS with the gate exchange).

#define T_STEPS  512
#define BATCH    64
#define DIM      1024
#define NG       4096
#define NBLK     256
#define PTHREADS 512
// ring slot: 64*1024 bf16 + 4KB pad (guards against any line prefetch)
#define HSLOT    ((size_t)(BATCH * DIM + 2048))

typedef __attribute__((ext_vector_type(8))) short frag8;   // 8 x bf16
typedef __attribute__((ext_vector_type(4))) float f32x4;

__device__ __forceinline__ short f2bf(float f) {
    union { float f; unsigned u; } v; v.f = f;
    unsigned r = v.u + 0x7fffu + ((v.u >> 16) & 1u);   // RNE
    return (short)(r >> 16);
}
__device__ __forceinline__ float sigm(float x) { return 1.0f / (1.0f + __expf(-x)); }
__device__ __forceinline__ float tanh_fast(float x) { return 1.0f - 2.0f / (__expf(2.0f * x) + 1.0f); }

// ---------------- prep kernels ----------------

__global__ __launch_bounds__(256)
void cast_transpose(const float* __restrict__ W, short* __restrict__ WT) {
    __shared__ float tile[32][33];
    int k0 = blockIdx.x * 32;
    int n0 = blockIdx.y * 32;
    int tx = threadIdx.x & 31, ty = threadIdx.x >> 5;
    #pragma unroll
    for (int i = 0; i < 32; i += 8)
        tile[ty + i][tx] = W[(size_t)(k0 + ty + i) * NG + n0 + tx];
    __syncthreads();
    #pragma unroll
    for (int i = 0; i < 32; i += 8)
        WT[(size_t)(n0 + ty + i) * DIM + k0 + tx] = f2bf(tile[tx][ty + i]);
}

__global__ __launch_bounds__(256)
void init_state(const float* __restrict__ c0, const float* __restrict__ h0,
                float* __restrict__ c, short* __restrict__ hring,
                unsigned* __restrict__ flags) {
    int i = blockIdx.x * 256 + threadIdx.x;     // 65536 threads
    c[i] = c0[i];
    hring[i] = f2bf(h0[i]);                     // slot 0
    if (i < NBLK * 32) flags[i] = 0u;
}

__global__ __launch_bounds__(256)
void xcast(const float* __restrict__ x, short* __restrict__ xb, int n8) {
    int i = blockIdx.x * 256 + threadIdx.x;
    if (i >= n8) return;
    const float4* p = (const float4*)(x + (size_t)i * 8);
    float4 a = p[0], b = p[1];
    frag8 v;
    v[0] = f2bf(a.x); v[1] = f2bf(a.y); v[2] = f2bf(a.z); v[3] = f2bf(a.w);
    v[4] = f2bf(b.x); v[5] = f2bf(b.y); v[6] = f2bf(b.z); v[7] = f2bf(b.w);
    *(frag8*)(xb + (size_t)i * 8) = v;
}

// xg^T[N=4096][M] = (A[M][1024] @ Wi)^T.  128x128 tile, BK=32, transposed store.
__global__ __launch_bounds__(256)
void xgemm(const short* __restrict__ A, const short* __restrict__ B,
           float* __restrict__ CT_, int M) {
    __shared__ short As[4096];
    __shared__ short Bs[4096];
    const int tid = threadIdx.x;
    const int w = tid >> 6, l = tid & 63, m = l & 15, q = l >> 4;
    const size_t abase = (size_t)blockIdx.x * 128 * DIM;
    const size_t bbase = (size_t)blockIdx.y * 128 * DIM;

    f32x4 acc[2][8];
    #pragma unroll
    for (int i = 0; i < 2; ++i)
        #pragma unroll
        for (int j = 0; j < 8; ++j) acc[i][j] = (f32x4){0.f, 0.f, 0.f, 0.f};

    for (int kc = 0; kc < 32; ++kc) {
        #pragma unroll
        for (int c2 = 0; c2 < 2; ++c2) {
            int t2 = c2 * 256 + tid;
            int seg = t2 >> 7, row = t2 & 127;
            const short* ga = A + abase + (size_t)row * DIM + kc * 32 + seg * 8;
            const short* gb = B + bbase + (size_t)row * DIM + kc * 32 + seg * 8;
            __builtin_amdgcn_global_load_lds(
                (const __attribute__((address_space(1))) void*)ga,
                (__attribute__((address_space(3))) void*)(As + t2 * 8), 16, 0, 0);
            __builtin_amdgcn_global_load_lds(
                (const __attribute__((address_space(1))) void*)gb,
                (__attribute__((address_space(3))) void*)(Bs + t2 * 8), 16, 0, 0);
        }
        __syncthreads();
        frag8 a0 = *(const frag8*)(As + (q * 128 + w * 32 + m) * 8);
        frag8 a1 = *(const frag8*)(As + (q * 128 + w * 32 + 16 + m) * 8);
        #pragma unroll
        for (int nt = 0; nt < 8; ++nt) {
            frag8 bf = *(const frag8*)(Bs + (q * 128 + nt * 16 + m) * 8);
            acc[0][nt] = __builtin_amdgcn_mfma_f32_16x16x32_bf16(a0, bf, acc[0][nt], 0, 0, 0);
            acc[1][nt] = __builtin_amdgcn_mfma_f32_16x16x32_bf16(a1, bf, acc[1][nt], 0, 0, 0);
        }
        __syncthreads();
    }
    // transposed store: CT_[col][row], 16B contiguous per lane
    #pragma unroll
    for (int mt = 0; mt < 2; ++mt)
        #pragma unroll
        for (int nt = 0; nt < 8; ++nt) {
            int row0 = blockIdx.x * 128 + w * 32 + mt * 16 + q * 4;
            int col  = blockIdx.y * 128 + nt * 16 + m;
            *(float4*)(CT_ + (size_t)col * M + row0) =
                make_float4(acc[mt][nt][0], acc[mt][nt][1], acc[mt][nt][2], acc[mt][nt][3]);
        }
}

// ---------------- persistent recurrence ----------------
// Block k owns 4 h-cols j0=4k (16 gate-cols). Wh slice 32KB LDS. 8 waves:
// (bt = w&3 batch-16-tile, kh = w>>2 K-half). Partial sums reduced in LDS.
__global__ __launch_bounds__(PTHREADS)
void lstm_persist(const float* __restrict__ xgT,    // [4096][M] f32
                  const short* __restrict__ WhT,    // [4096][1024] bf16
                  const float* __restrict__ bias,
                  float* __restrict__ cstate,       // [64][1024] f32
                  short* __restrict__ hring,        // CT slots of HSLOT
                  float* __restrict__ y,            // out + chunk offset
                  unsigned* __restrict__ flags,     // NBLK x 32 uints (128B pad)
                  int gstep0, int CTC, int M) {
    __shared__ short whs[2048 * 8];     // 32 KB
    __shared__ float gsm2[2][64][17];   // 8.5 KB partials
    const int tid = threadIdx.x;
    const int w = tid >> 6, l = tid & 63, m = l & 15, q4 = l >> 4;
    const int bt = w & 3, kh = w >> 2;
    const int j0 = blockIdx.x * 4;

    // stage Wh slice: whs[kidx 0..31][lane 64][8]: col cc=l&15, k=kidx*32+(l>>4)*8
    for (int idx = tid; idx < 2048; idx += PTHREADS) {
        int kcc = idx >> 6, ll = idx & 63, cc = ll & 15, qq = ll >> 4;
        int gcol = (cc >> 2) * DIM + j0 + (cc & 3);
        *(frag8*)(whs + idx * 8) =
            *(const frag8*)(WhT + (size_t)gcol * DIM + kcc * 32 + qq * 8);
    }

    const int eb = tid >> 2, ej = tid & 3;   // elementwise mapping (tid < 256)
    float creg = 0.f, bv0 = 0.f, bv1 = 0.f, bv2 = 0.f, bv3 = 0.f;
    if (tid < 256) {
        creg = cstate[eb * DIM + j0 + ej];
        bv0 = bias[0 * DIM + j0 + ej];
        bv1 = bias[1 * DIM + j0 + ej];
        bv2 = bias[2 * DIM + j0 + ej];
        bv3 = bias[3 * DIM + j0 + ej];
    }
    __syncthreads();

    for (int t = 0; t < CTC; ++t) {
        // prefetch gate inputs for this step (chunk-static, independent of h)
        float xv0 = 0.f, xv1 = 0.f, xv2 = 0.f, xv3 = 0.f;
        if (tid < 256) {
            const size_t r = (size_t)t * BATCH + eb;
            xv0 = xgT[(size_t)(0 * DIM + j0 + ej) * M + r];
            xv1 = xgT[(size_t)(1 * DIM + j0 + ej) * M + r];
            xv2 = xgT[(size_t)(2 * DIM + j0 + ej) * M + r];
            xv3 = xgT[(size_t)(3 * DIM + j0 + ej) * M + r];
        }

        // wait for h(t) to be globally visible (skip t=0: init/prev launch)
        if (t > 0 && w == 0) {
            const unsigned target = (unsigned)(gstep0 + t);
            for (;;) {
                bool ok = true;
                #pragma unroll
                for (int i = 0; i < 4; ++i) {
                    unsigned f = __hip_atomic_load(&flags[(l * 4 + i) * 32],
                        __ATOMIC_RELAXED, __HIP_MEMORY_SCOPE_AGENT);
                    ok &= (f >= target);
                }
                if (__all(ok)) break;
                __builtin_amdgcn_s_sleep(2);
            }
        }
        __syncthreads();   // gates h reads below (also orders gsm2 reuse)

        // h(t) @ Wh-slice, K-half per wave
        const short* hrow = hring + (size_t)t * HSLOT
                          + (size_t)(bt * 16 + m) * DIM + kh * 512;
        f32x4 acc = {0.f, 0.f, 0.f, 0.f};
        #pragma unroll
        for (int kc = 0; kc < 16; ++kc) {
            frag8 a = *(const frag8*)(hrow + kc * 32 + q4 * 8);
            frag8 b = *(const frag8*)(whs + ((kh * 16 + kc) * 64 + l) * 8);
            acc = __builtin_amdgcn_mfma_f32_16x16x32_bf16(a, b, acc, 0, 0, 0);
        }
        #pragma unroll
        for (int r = 0; r < 4; ++r)
            gsm2[kh][bt * 16 + q4 * 4 + r][m] = acc[r];   // col m = packed gate-col
        __syncthreads();

        if (tid < 256) {
            const float gi = sigm(     gsm2[0][eb][ej]      + gsm2[1][eb][ej]      + xv0 + bv0);
            const float gf = sigm(     gsm2[0][eb][4 + ej]  + gsm2[1][eb][4 + ej]  + xv1 + bv1);
            const float gg = tanh_fast(gsm2[0][eb][8 + ej]  + gsm2[1][eb][8 + ej]  + xv2 + bv2);
            const float go = sigm(     gsm2[0][eb][12 + ej] + gsm2[1][eb][12 + ej] + xv3 + bv3);
            creg = gf * creg + gi * gg;
            const float hn = go * tanh_fast(creg);

            // y: pack 4 lanes -> one float4 store
            const float y1 = __shfl_down(hn, 1), y2 = __shfl_down(hn, 2), y3 = __shfl_down(hn, 3);
            if (ej == 0)
                *(float4*)(y + ((size_t)t * BATCH + eb) * DIM + j0) = make_float4(hn, y1, y2, y3);

            // h: pack 4 bf16 -> one 8B write-through store to next ring slot
            unsigned hb0 = (unsigned)(unsigned short)f2bf(hn);
            unsigned hb1 = __shfl_down(hb0, 1);
            unsigned hb2 = __shfl_down(hb0, 2);
            unsigned hb3 = __shfl_down(hb0, 3);
            if (ej == 0) {
                const int dslot = (t == CTC - 1) ? 0 : (t + 1);
                unsigned long long v = (unsigned long long)(hb0 | (hb1 << 16))
                                     | ((unsigned long long)(hb2 | (hb3 << 16)) << 32);
                __hip_atomic_store(
                    (unsigned long long*)(hring + (size_t)dslot * HSLOT + eb * DIM + j0),
                    v, __ATOMIC_RELAXED, __HIP_MEMORY_SCOPE_AGENT);
            }
        }

        if (t < CTC - 1) {
            // drain write-through stores to the coherence point, then signal
            asm volatile("s_waitcnt vmcnt(0)" ::: "memory");
            __syncthreads();
            if (tid == 0)
                __hip_atomic_store(&flags[blockIdx.x * 32], (unsigned)(gstep0 + t + 1),
                                   __ATOMIC_RELAXED, __HIP_MEMORY_SCOPE_AGENT);
        }
    }
    if (tid < 256) cstate[eb * DIM + j0 + ej] = creg;
}

// ---------------- host ----------------
extern "C" void kernel_launch(void* const* d_in, const int* in_sizes, int n_in,
                              void* d_out, int out_size, void* d_ws, size_t ws_size,
                              hipStream_t stream) {
    const float* x  = (const float*)d_in[0];
    const float* c0 = (const float*)d_in[1];
    const float* h0 = (const float*)d_in[2];
    const float* Wi = (const float*)d_in[3];
    const float* Wh = (const float*)d_in[4];
    const float* b  = (const float*)d_in[5];
    float* out = (float*)d_out;

    char* ws = (char*)d_ws;
    short*    WiT   = (short*)(ws);                    // 8 MB
    short*    WhT   = (short*)(ws + 8388608);          // 8 MB
    float*    c     = (float*)(ws + 16777216);         // 256 KB
    unsigned* flags = (unsigned*)(ws + 17039360);      // 32 KB (256 x 128B)
    const size_t fixed = 17072128;

    // per-CT bytes: hring CT*HSLOT*2 + xbf CT*128KB + xgT CT*1MB
    const size_t perCT = HSLOT * 2 + 131072 + 1048576;   // 1,314,816
    int CT = 2;
    const int cands[9] = {512, 256, 128, 64, 32, 16, 8, 4, 2};
    for (int i = 0; i < 9; ++i)
        if (fixed + (size_t)cands[i] * perCT <= ws_size) { CT = cands[i]; break; }

    short* hring = (short*)(ws + fixed);
    short* xbf   = (short*)(ws + fixed + (size_t)CT * HSLOT * 2);
    float* xgT   = (float*)(ws + fixed + (size_t)CT * (HSLOT * 2 + 131072));
    const int M = CT * BATCH;

    cast_transpose<<<dim3(DIM / 32, NG / 32), 256, 0, stream>>>(Wi, WiT);
    cast_transpose<<<dim3(DIM / 32, NG / 32), 256, 0, stream>>>(Wh, WhT);
    init_state<<<dim3(BATCH * DIM / 256), 256, 0, stream>>>(c0, h0, c, hring, flags);

    const int nchunks = T_STEPS / CT;
    for (int ch = 0; ch < nchunks; ++ch) {
        const size_t xoff = (size_t)ch * CT * BATCH * DIM;
        const int n8 = CT * BATCH * DIM / 8;
        xcast<<<dim3((n8 + 255) / 256), 256, 0, stream>>>(x + xoff, xbf, n8);
        xgemm<<<dim3(M / 128, NG / 128), 256, 0, stream>>>(xbf, WiT, xgT, M);
        lstm_persist<<<dim3(NBLK), PTHREADS, 0, stream>>>(
            xgT, WhT, b, c, hring, out + xoff, flags, ch * CT, CT, M);
    }
}